// Round 9
// baseline (176.272 us; speedup 1.0000x reference)
//
#include <hip/hip_runtime.h>
#include <hip/hip_bf16.h>
#include <stdint.h>
#include <stddef.h>
#include <type_traits>

typedef __bf16 bf16_t;
typedef __attribute__((ext_vector_type(4))) __bf16 bf16x4;
typedef __attribute__((ext_vector_type(8))) __bf16 bf16x8;
typedef __attribute__((ext_vector_type(4))) float floatx4;

#define GLD16(gp, lp) __builtin_amdgcn_global_load_lds(                      \
    (__attribute__((address_space(1))) void*)(gp),                           \
    (__attribute__((address_space(3))) void*)(lp), 16, 0, 0)

// ---------------------------------------------------------------------------
// Fused prep: [0,2048) x f32->bf16 | [2048,2816) transpose_w | [2816,3072) transpose_wo
// Q weights (z==0) pre-scaled by (1/sqrt(64))*log2(e).
// ---------------------------------------------------------------------------
__global__ __launch_bounds__(256) void prep(
    const float* __restrict__ x, const float* __restrict__ Wq,
    const float* __restrict__ Wk, const float* __restrict__ Wv,
    const float* __restrict__ Wo, bf16_t* __restrict__ XB,
    bf16_t* __restrict__ WT, bf16_t* __restrict__ WoT) {
  __shared__ bf16_t t[64][65];
  int bx = blockIdx.x;
  const int tid = threadIdx.x;
  if (bx < 2048) {  // convert x
    const int i = (bx * 256 + tid) * 8;
    const float4 v0 = *(const float4*)(x + i);
    const float4 v1 = *(const float4*)(x + i + 4);
    bf16x8 o = {(bf16_t)v0.x, (bf16_t)v0.y, (bf16_t)v0.z, (bf16_t)v0.w,
                (bf16_t)v1.x, (bf16_t)v1.y, (bf16_t)v1.z, (bf16_t)v1.w};
    *(bf16x8*)(XB + i) = o;
    return;
  }
  bx -= 2048;
  const int g = tid >> 6, l = tid & 63;
  if (bx < 768) {  // Wq/Wk/Wv [16][1024][64] -> WT [3072][1024]
    const int d0 = (bx & 15) * 64, h = (bx >> 4) & 15, z = bx >> 8;
    const float* W = (z == 0) ? Wq : (z == 1) ? Wk : Wv;
    const float scl = (z == 0) ? 0.18033688011112042f : 1.0f;
    const float* src = W + (size_t)h * 65536 + (size_t)d0 * 64;  // [d][hd]
    #pragma unroll
    for (int i = 0; i < 16; ++i) { int r = g * 16 + i; t[r][l] = (bf16_t)(src[(size_t)r * 64 + l] * scl); }
    __syncthreads();
    bf16_t* dst = WT + ((size_t)z * 1024 + h * 64) * 1024 + d0;
    #pragma unroll
    for (int i = 0; i < 16; ++i) { int c = g * 16 + i; dst[(size_t)c * 1024 + l] = t[l][c]; }
  } else {  // Wo [1024][1024] -> WoT
    bx -= 768;
    const int r0 = (bx & 15) * 64, c0 = (bx >> 4) * 64;
    #pragma unroll
    for (int i = 0; i < 16; ++i) { int r = g * 16 + i; t[r][l] = (bf16_t)Wo[(size_t)(r0 + r) * 1024 + c0 + l]; }
    __syncthreads();
    #pragma unroll
    for (int i = 0; i < 16; ++i) { int c = g * 16 + i; WoT[(size_t)(c0 + c) * 1024 + r0 + l] = t[l][c]; }
  }
}

// ---------------------------------------------------------------------------
// GEMM body, BK=64: C[m][n] = sum_k A[m][k]*Bt[n][k] (+f32 bias).
// 128x128 tile, GLD16 async staging, XOR slot swizzle, LDS 32KB -> 4 blk/CU.
// ---------------------------------------------------------------------------
template <bool BIAS, typename OutT>
__device__ __forceinline__ void gemm_body(
    const bf16_t* __restrict__ A, const bf16_t* __restrict__ Bt,
    OutT* __restrict__ C, const float* __restrict__ bias,
    int K, int lda, int ldb, int ldc, int m0, int n0,
    bf16_t* As, bf16_t* Bs) {
  const int tid = threadIdx.x;
  const int lane = tid & 63, w = tid >> 6;
  const int qd = lane >> 4, ln = lane & 15;
  const int wm = (w & 1) * 64, wn = (w >> 1) * 64;

  const floatx4 z4 = {0.f, 0.f, 0.f, 0.f};
  floatx4 acc[4][4];
  #pragma unroll
  for (int i = 0; i < 4; ++i)
    #pragma unroll
    for (int j = 0; j < 4; ++j) acc[i][j] = z4;

  for (int k0 = 0; k0 < K; k0 += 64) {
    #pragma unroll
    for (int i = 0; i < 4; ++i) {
      const int c = tid + i * 256;              // 16B chunk id, 1024 per tile
      const int row = c >> 3;                   // 0..127
      const int sg = (c & 7) ^ (row & 7);       // swizzled slot
      GLD16(A + (size_t)(m0 + row) * lda + k0 + sg * 8, As + (size_t)(w * 64 + i * 256) * 8);
      GLD16(Bt + (size_t)(n0 + row) * ldb + k0 + sg * 8, Bs + (size_t)(w * 64 + i * 256) * 8);
    }
    __syncthreads();
    #pragma unroll
    for (int h = 0; h < 2; ++h) {
      bf16x8 af[4], bfr[4];
      #pragma unroll
      for (int t = 0; t < 4; ++t) {
        const int ra = wm + t * 16 + ln;
        const int rb = wn + t * 16 + ln;
        af[t]  = *(const bf16x8*)(As + (size_t)ra * 64 + (((h * 4 + qd) ^ (ra & 7)) * 8));
        bfr[t] = *(const bf16x8*)(Bs + (size_t)rb * 64 + (((h * 4 + qd) ^ (rb & 7)) * 8));
      }
      #pragma unroll
      for (int mt = 0; mt < 4; ++mt)
        #pragma unroll
        for (int nt = 0; nt < 4; ++nt)
          acc[mt][nt] = __builtin_amdgcn_mfma_f32_16x16x32_bf16(af[mt], bfr[nt], acc[mt][nt], 0, 0, 0);
    }
    __syncthreads();
  }

  #pragma unroll
  for (int nt = 0; nt < 4; ++nt) {
    const int col = n0 + wn + nt * 16 + ln;
    const float bv = BIAS ? bias[col] : 0.f;
    #pragma unroll
    for (int mt = 0; mt < 4; ++mt) {
      const int row = m0 + wm + mt * 16 + qd * 4;  // C layout: col=lane&15, row=quad*4+reg
      #pragma unroll
      for (int r = 0; r < 4; ++r)
        C[(size_t)(row + r) * ldc + col] = (OutT)(acc[mt][nt][r] + bv);
    }
  }
}

// Fused projections: blocks [0,512) QK gemm (C1[4096][2048]),
// blocks [512,768) V gemm directly transposed (VT[1024][4096]).
__global__ __launch_bounds__(256) void proj_gemm(
    const bf16_t* __restrict__ XB, const bf16_t* __restrict__ WT,
    bf16_t* __restrict__ C1, bf16_t* __restrict__ VT) {
  __shared__ __align__(16) bf16_t As[128 * 64];
  __shared__ __align__(16) bf16_t Bs[128 * 64];
  int bx = blockIdx.x;
  if (bx < 512) {
    gemm_body<false, bf16_t>(XB, WT, C1, nullptr, 1024, 1024, 1024, 2048,
                             (bx & 31) * 128, (bx >> 5) * 128, As, Bs);
  } else {
    bx -= 512;
    gemm_body<false, bf16_t>(WT + (size_t)2048 * 1024, XB, VT, nullptr,
                             1024, 1024, 1024, 4096,
                             (bx & 7) * 128, (bx >> 3) * 128, As, Bs);
  }
}

// Output projection (+bias) -> f32
__global__ __launch_bounds__(256) void out_gemm(
    const bf16_t* __restrict__ AO, const bf16_t* __restrict__ WoT,
    float* __restrict__ C, const float* __restrict__ bias) {
  __shared__ __align__(16) bf16_t As[128 * 64];
  __shared__ __align__(16) bf16_t Bs[128 * 64];
  gemm_body<true, float>(AO, WoT, C, bias, 1024, 1024, 1024, 1024,
                         blockIdx.x * 128, blockIdx.y * 128, As, Bs);
}

// ---------------------------------------------------------------------------
// Flash attention v11 (= round-4 v9, measured best, + peeled final s-tile):
//  - XCD-local (b,h) mapping; balance map {j, 15-j, 16+j, 31-j} (measured
//    best; split-K variants measured worse -> flash is work-bound, not
//    makespan-bound).
//  - Ones-MFMA row-sum; V-frag preload before softmax; s_setprio.
//  - NEW: final (masked) s-tile peeled out of the loop via compile-time
//    specialization -- the causal compare/cndmask chain (~32 VALU/lane/tile)
//    is guaranteed absent from the 15/16 unmasked tiles.
//  - LDS 40960 B -> 4 blocks/CU; K/V XOR-slot-swizzled (pre-swizzled global
//    source + linear GLD16 dest); Ps 8B-slot swizzle; Q pre-scaled.
// ---------------------------------------------------------------------------
__global__ __launch_bounds__(256, 4) void flash_attn(
    const bf16_t* __restrict__ C1, const bf16_t* __restrict__ VT,
    bf16_t* __restrict__ AO) {
  __shared__ __align__(16) bf16_t Ks[2][64 * 64];  // 16384 B
  __shared__ __align__(16) bf16_t Vs[2][64 * 64];  // 16384 B
  __shared__ __align__(16) bf16_t Ps[4][16 * 64];  //  8192 B  (total 40960)

  const int bid = blockIdx.x;
  const int g = bid & 31;             // (b,h) group; XCD = g & 7
  const int b = g >> 4, h = g & 15;
  const int v = bid >> 5, j = v & 7, sel = v >> 3;
  const int qt = (sel == 0) ? j : (sel == 1) ? 15 - j : (sel == 2) ? 16 + j : 31 - j;

  const int tid = threadIdx.x, lane = tid & 63, w = tid >> 6;
  const int qd = lane >> 4, ln = lane & 15;
  const bf16_t* Qb = C1 + (size_t)b * 2048 * 2048;

  // Q B-frags: lane (qd,ln): col=ln -> q, k=qd*8+j -> d (pre-scaled by SCL)
  bf16x8 qf0, qf1;
  {
    const bf16_t* qp = Qb + (size_t)(qt * 64 + w * 16 + ln) * 2048 + h * 64 + qd * 8;
    qf0 = *(const bf16x8*)qp;
    qf1 = *(const bf16x8*)(qp + 32);
  }
  const floatx4 z4 = {0.f, 0.f, 0.f, 0.f};
  floatx4 oacc[4];  // [t][r]: O[q_local=qd*4+r][hd=t*16+ln]
  #pragma unroll
  for (int t = 0; t < 4; ++t) oacc[t] = z4;
  floatx4 osum = z4;  // osum[r] = sum_s P[q=4qd+r][s], replicated over ln
  const bf16_t one = (bf16_t)1.0f;
  const bf16x8 vone = {one, one, one, one, one, one, one, one};

  const bf16_t* Kg = Qb + 1024 + h * 64;                       // + s*2048 + d
  const bf16_t* Vg = VT + (size_t)(h * 64) * 4096 + b * 2048;  // + hd*4096 + t

  const int r0 = tid >> 3;
  const int g0 = ((tid & 7) ^ (r0 & 7)) * 8;

  auto STAGE = [&](int BUF, int SOFF) {
    GLD16(Kg + (size_t)(SOFF + r0) * 2048 + g0,      &Ks[BUF][w * 512]);
    GLD16(Kg + (size_t)(SOFF + r0 + 32) * 2048 + g0, &Ks[BUF][w * 512 + 2048]);
    GLD16(Vg + (size_t)r0 * 4096 + SOFF + g0,        &Vs[BUF][w * 512]);
    GLD16(Vg + (size_t)(r0 + 32) * 4096 + SOFF + g0, &Vs[BUF][w * 512 + 2048]);
  };

  STAGE(0, 0);  // prologue: tile 0

  const int e2 = (ln & 7) << 1;       // Ps 8B-slot swizzle key
  const int swf = qd ^ (ln & 7);      // K/V frag slot swizzle (row&7 == ln&7)

  // One s-tile: QK^T -> softmax -> Ps round-trip -> PV (+ row-sum MFMA).
  auto TILE = [&](auto LAST, int st) {
    const int bi = st & 1;
    __syncthreads();  // drains vmcnt: tile st staged; WAR-safe for buf bi^1
    if (!LAST.value) STAGE(bi ^ 1, (st + 1) * 64);

    // S^T = K Q^T : lane (qd,ln) gets P[q=ln][s=nt*16+qd*4+r]
    floatx4 sa[4];
    __builtin_amdgcn_s_setprio(1);
    #pragma unroll
    for (int nt = 0; nt < 4; ++nt) {
      const bf16_t* kp = &Ks[bi][(nt * 16 + ln) * 64];
      bf16x8 kf0 = *(const bf16x8*)(kp + swf * 8);
      bf16x8 kf1 = *(const bf16x8*)(kp + (swf ^ 4) * 8);
      floatx4 t0 = z4;
      t0 = __builtin_amdgcn_mfma_f32_16x16x32_bf16(kf0, qf0, t0, 0, 0, 0);
      t0 = __builtin_amdgcn_mfma_f32_16x16x32_bf16(kf1, qf1, t0, 0, 0, 0);
      sa[nt] = t0;
    }
    __builtin_amdgcn_s_setprio(0);

    // V-frag preload (independent of Ps round-trip)
    bf16x8 vf0[4], vf1[4];
    #pragma unroll
    for (int t = 0; t < 4; ++t) {
      const bf16_t* vp = &Vs[bi][(t * 16 + ln) * 64];
      vf0[t] = *(const bf16x8*)(vp + swf * 8);
      vf1[t] = *(const bf16x8*)(vp + (swf ^ 4) * 8);
    }

    // softmax -> Ps (swizzled, wave-private; in-wave DS order)
    #pragma unroll
    for (int nt = 0; nt < 4; ++nt) {
      float p[4];
      #pragma unroll
      for (int r = 0; r < 4; ++r) {
        float v2 = sa[nt][r];
        if (LAST.value && (nt * 16 + qd * 4 + r) > (w * 16 + ln)) v2 = -1e30f;
        p[r] = __builtin_amdgcn_exp2f(v2);
      }
      bf16x4 pk = {(bf16_t)p[0], (bf16_t)p[1], (bf16_t)p[2], (bf16_t)p[3]};
      *(bf16x4*)(&Ps[w][ln * 64 + (((nt * 4 + qd) ^ e2) << 2)]) = pk;
    }
    bf16x8 pa0 = *(const bf16x8*)(&Ps[w][ln * 64 + ((((qd << 1)    ) ^ e2) << 2)]);
    bf16x8 pa1 = *(const bf16x8*)(&Ps[w][ln * 64 + ((((qd << 1) + 8) ^ e2) << 2)]);

    // PV: oacc += P * V;  osum += P * 1 (row sums on the MFMA pipe)
    __builtin_amdgcn_s_setprio(1);
    #pragma unroll
    for (int t = 0; t < 4; ++t) {
      oacc[t] = __builtin_amdgcn_mfma_f32_16x16x32_bf16(pa0, vf0[t], oacc[t], 0, 0, 0);
      oacc[t] = __builtin_amdgcn_mfma_f32_16x16x32_bf16(pa1, vf1[t], oacc[t], 0, 0, 0);
    }
    osum = __builtin_amdgcn_mfma_f32_16x16x32_bf16(pa0, vone, osum, 0, 0, 0);
    osum = __builtin_amdgcn_mfma_f32_16x16x32_bf16(pa1, vone, osum, 0, 0, 0);
    __builtin_amdgcn_s_setprio(0);
  };

  for (int st = 0; st < qt; ++st)
    TILE(std::integral_constant<bool, false>{}, st);
  TILE(std::integral_constant<bool, true>{}, qt);

  // epilogue: O[q][hd] /= l[q]; osum[r] already holds l(q=4qd+r) in-lane
  #pragma unroll
  for (int r = 0; r < 4; ++r) {
    const float lr = 1.0f / osum[r];
    #pragma unroll
    for (int t = 0; t < 4; ++t) {
      const int col = h * 64 + t * 16 + ln;
      const int row = b * 2048 + qt * 64 + w * 16 + qd * 4 + r;
      AO[(size_t)row * 1024 + col] = (bf16_t)(oacc[t][r] * lr);
    }
  }
}

// ---------------------------------------------------------------------------
extern "C" void kernel_launch(void* const* d_in, const int* in_sizes, int n_in,
                              void* d_out, int out_size, void* d_ws, size_t ws_size,
                              hipStream_t stream) {
  const float* x  = (const float*)d_in[0];
  const float* Wq = (const float*)d_in[1];
  const float* Wk = (const float*)d_in[2];
  const float* Wv = (const float*)d_in[3];
  const float* Wo = (const float*)d_in[4];
  const float* bo = (const float*)d_in[5];
  float* out = (float*)d_out;

  // Workspace (33.56 MB, proven safe):
  bf16_t* WT  = (bf16_t*)d_ws;               // [3072][1024] 6.29 MB (Q|K|V weight rows)
  bf16_t* WoT = WT + (size_t)3072 * 1024;    // [1024][1024] 2.10 MB
  bf16_t* C1  = WoT + (size_t)1024 * 1024;   // [4096][2048] 16.78 MB (Q|K cols)
  bf16_t* AO  = C1 + (size_t)4096 * 2048;    // [4096][1024] 8.39 MB
  // d_out doubles as scratch (16.78 MB; fully overwritten by final gemm):
  bf16_t* XB  = (bf16_t*)d_out;              // [4096][1024] bf16, lower half
  bf16_t* VT  = XB + (size_t)4096 * 1024;    // [1024][4096] bf16, upper half

  prep<<<dim3(3072), 256, 0, stream>>>(x, Wq, Wk, Wv, Wo, XB, WT, WoT);
  proj_gemm<<<dim3(768), 256, 0, stream>>>(XB, WT, C1, VT);
  flash_attn<<<dim3(1024), 256, 0, stream>>>(C1, VT, AO);
  out_gemm<<<dim3(32, 8), 256, 0, stream>>>(AO, WoT, out, bo);
}

// Round 11
// 168.493 us; speedup vs baseline: 1.0462x; 1.0462x over previous
//
#include <hip/hip_runtime.h>
#include <hip/hip_bf16.h>
#include <stdint.h>
#include <stddef.h>

typedef __bf16 bf16_t;
typedef __attribute__((ext_vector_type(4))) __bf16 bf16x4;
typedef __attribute__((ext_vector_type(8))) __bf16 bf16x8;
typedef __attribute__((ext_vector_type(4))) float floatx4;

#define GLD16(gp, lp) __builtin_amdgcn_global_load_lds(                      \
    (__attribute__((address_space(1))) void*)(gp),                           \
    (__attribute__((address_space(3))) void*)(lp), 16, 0, 0)

// ---------------------------------------------------------------------------
// Fused prep: [0,2048) x f32->bf16 | [2048,2816) transpose_w | [2816,3072) transpose_wo
// Q weights (z==0) pre-scaled by (1/sqrt(64))*log2(e).
// ---------------------------------------------------------------------------
__global__ __launch_bounds__(256) void prep(
    const float* __restrict__ x, const float* __restrict__ Wq,
    const float* __restrict__ Wk, const float* __restrict__ Wv,
    const float* __restrict__ Wo, bf16_t* __restrict__ XB,
    bf16_t* __restrict__ WT, bf16_t* __restrict__ WoT) {
  __shared__ bf16_t t[64][65];
  int bx = blockIdx.x;
  const int tid = threadIdx.x;
  if (bx < 2048) {  // convert x
    const int i = (bx * 256 + tid) * 8;
    const float4 v0 = *(const float4*)(x + i);
    const float4 v1 = *(const float4*)(x + i + 4);
    bf16x8 o = {(bf16_t)v0.x, (bf16_t)v0.y, (bf16_t)v0.z, (bf16_t)v0.w,
                (bf16_t)v1.x, (bf16_t)v1.y, (bf16_t)v1.z, (bf16_t)v1.w};
    *(bf16x8*)(XB + i) = o;
    return;
  }
  bx -= 2048;
  const int g = tid >> 6, l = tid & 63;
  if (bx < 768) {  // Wq/Wk/Wv [16][1024][64] -> WT [3072][1024]
    const int d0 = (bx & 15) * 64, h = (bx >> 4) & 15, z = bx >> 8;
    const float* W = (z == 0) ? Wq : (z == 1) ? Wk : Wv;
    const float scl = (z == 0) ? 0.18033688011112042f : 1.0f;
    const float* src = W + (size_t)h * 65536 + (size_t)d0 * 64;  // [d][hd]
    #pragma unroll
    for (int i = 0; i < 16; ++i) { int r = g * 16 + i; t[r][l] = (bf16_t)(src[(size_t)r * 64 + l] * scl); }
    __syncthreads();
    bf16_t* dst = WT + ((size_t)z * 1024 + h * 64) * 1024 + d0;
    #pragma unroll
    for (int i = 0; i < 16; ++i) { int c = g * 16 + i; dst[(size_t)c * 1024 + l] = t[l][c]; }
  } else {  // Wo [1024][1024] -> WoT
    bx -= 768;
    const int r0 = (bx & 15) * 64, c0 = (bx >> 4) * 64;
    #pragma unroll
    for (int i = 0; i < 16; ++i) { int r = g * 16 + i; t[r][l] = (bf16_t)Wo[(size_t)(r0 + r) * 1024 + c0 + l]; }
    __syncthreads();
    #pragma unroll
    for (int i = 0; i < 16; ++i) { int c = g * 16 + i; WoT[(size_t)(c0 + c) * 1024 + r0 + l] = t[l][c]; }
  }
}

// ---------------------------------------------------------------------------
// GEMM body, BK=64: C[m][n] = sum_k A[m][k]*Bt[n][k] (+f32 bias).
// M-tile 128; N-tile = NT*32 (NT = n-frags per wave: 4 -> 128, 2 -> 64).
// GLD16 async staging, XOR slot swizzle, 16 K-iters for K=1024.
// B tile = NT*32 rows = NT*256 chunks -> NT staging iterations (round-10
// bug: NT/2 iterations left half of B unstaged -> absmax 90).
// NT=4: LDS 32KB (identical to round-8 proven form). NT=2: LDS 24KB, used
// by out_gemm to reach 2 blocks/CU (was 1 block/CU = latency-bound).
// ---------------------------------------------------------------------------
template <bool BIAS, typename OutT, int NT>
__device__ __forceinline__ void gemm_body(
    const bf16_t* __restrict__ A, const bf16_t* __restrict__ Bt,
    OutT* __restrict__ C, const float* __restrict__ bias,
    int K, int lda, int ldb, int ldc, int m0, int n0,
    bf16_t* As, bf16_t* Bs) {
  const int tid = threadIdx.x;
  const int lane = tid & 63, w = tid >> 6;
  const int qd = lane >> 4, ln = lane & 15;
  const int wm = (w & 1) * 64, wn = (w >> 1) * (NT * 16);

  const floatx4 z4 = {0.f, 0.f, 0.f, 0.f};
  floatx4 acc[4][NT];
  #pragma unroll
  for (int i = 0; i < 4; ++i)
    #pragma unroll
    for (int j = 0; j < NT; ++j) acc[i][j] = z4;

  for (int k0 = 0; k0 < K; k0 += 64) {
    #pragma unroll
    for (int i = 0; i < 4; ++i) {  // A: 128 rows -> 1024 chunks
      const int c = tid + i * 256;
      const int row = c >> 3;
      const int sg = (c & 7) ^ (row & 7);
      GLD16(A + (size_t)(m0 + row) * lda + k0 + sg * 8, As + (size_t)(w * 64 + i * 256) * 8);
    }
    #pragma unroll
    for (int i = 0; i < NT; ++i) {  // B: NT*32 rows -> NT*256 chunks
      const int c = tid + i * 256;
      const int row = c >> 3;
      const int sg = (c & 7) ^ (row & 7);
      GLD16(Bt + (size_t)(n0 + row) * ldb + k0 + sg * 8, Bs + (size_t)(w * 64 + i * 256) * 8);
    }
    __syncthreads();
    #pragma unroll
    for (int h = 0; h < 2; ++h) {
      bf16x8 af[4], bfr[NT];
      #pragma unroll
      for (int t = 0; t < 4; ++t) {
        const int ra = wm + t * 16 + ln;
        af[t]  = *(const bf16x8*)(As + (size_t)ra * 64 + (((h * 4 + qd) ^ (ra & 7)) * 8));
      }
      #pragma unroll
      for (int t = 0; t < NT; ++t) {
        const int rb = wn + t * 16 + ln;
        bfr[t] = *(const bf16x8*)(Bs + (size_t)rb * 64 + (((h * 4 + qd) ^ (rb & 7)) * 8));
      }
      #pragma unroll
      for (int mt = 0; mt < 4; ++mt)
        #pragma unroll
        for (int nt = 0; nt < NT; ++nt)
          acc[mt][nt] = __builtin_amdgcn_mfma_f32_16x16x32_bf16(af[mt], bfr[nt], acc[mt][nt], 0, 0, 0);
    }
    __syncthreads();
  }

  #pragma unroll
  for (int nt = 0; nt < NT; ++nt) {
    const int col = n0 + wn + nt * 16 + ln;
    const float bv = BIAS ? bias[col] : 0.f;
    #pragma unroll
    for (int mt = 0; mt < 4; ++mt) {
      const int row = m0 + wm + mt * 16 + qd * 4;  // C layout: col=lane&15, row=quad*4+reg
      #pragma unroll
      for (int r = 0; r < 4; ++r)
        C[(size_t)(row + r) * ldc + col] = (OutT)(acc[mt][nt][r] + bv);
    }
  }
}

// Fused projections: blocks [0,512) QK gemm (C1[4096][2048]),
// blocks [512,768) V gemm directly transposed (VT[1024][4096]).
__global__ __launch_bounds__(256) void proj_gemm(
    const bf16_t* __restrict__ XB, const bf16_t* __restrict__ WT,
    bf16_t* __restrict__ C1, bf16_t* __restrict__ VT) {
  __shared__ __align__(16) bf16_t As[128 * 64];
  __shared__ __align__(16) bf16_t Bs[128 * 64];
  int bx = blockIdx.x;
  if (bx < 512) {
    gemm_body<false, bf16_t, 4>(XB, WT, C1, nullptr, 1024, 1024, 1024, 2048,
                                (bx & 31) * 128, (bx >> 5) * 128, As, Bs);
  } else {
    bx -= 512;
    gemm_body<false, bf16_t, 4>(WT + (size_t)2048 * 1024, XB, VT, nullptr,
                                1024, 1024, 1024, 4096,
                                (bx & 7) * 128, (bx >> 3) * 128, As, Bs);
  }
}

// Output projection (+bias) -> f32. 128x64 tiles -> grid 512 = 2 blocks/CU
// (was 256 = 1/CU, latency-bound: 1 wave/SIMD, nothing to hide GLD16 under).
__global__ __launch_bounds__(256) void out_gemm(
    const bf16_t* __restrict__ AO, const bf16_t* __restrict__ WoT,
    float* __restrict__ C, const float* __restrict__ bias) {
  __shared__ __align__(16) bf16_t As[128 * 64];
  __shared__ __align__(16) bf16_t Bs[64 * 64];
  gemm_body<true, float, 2>(AO, WoT, C, bias, 1024, 1024, 1024, 1024,
                            blockIdx.x * 128, blockIdx.y * 64, As, Bs);
}

// ---------------------------------------------------------------------------
// Flash attention v9 (round-4 measured best, verbatim):
//  - XCD-local (b,h) mapping (g = bid&31 -> (b,h); XCD = g&7 constant per
//    (b,h); co-CU blocks share the SAME (b,h) -> K/V L2/L1-local).
//  - Balance map {j, 15-j, 16+j, 31-j}: per-CU qt-set degrades 4->3->2->1
//    blocks gradually. (Split-K and tile-peel variants both measured worse:
//    flash is work/LDS-throughput-bound, not makespan- or mask-VALU-bound.)
//  - Ones-MFMA row-sum on the MFMA pipe; V-frag preload before softmax;
//    s_setprio(1) around MFMA clusters.
//  - LDS 40960 B -> 4 blocks/CU; K/V XOR-slot-swizzled via pre-swizzled
//    global source + linear GLD16 dest; Ps 8B-slot swizzle; Q pre-scaled.
// ---------------------------------------------------------------------------
__global__ __launch_bounds__(256, 4) void flash_attn(
    const bf16_t* __restrict__ C1, const bf16_t* __restrict__ VT,
    bf16_t* __restrict__ AO) {
  __shared__ __align__(16) bf16_t Ks[2][64 * 64];  // 16384 B
  __shared__ __align__(16) bf16_t Vs[2][64 * 64];  // 16384 B
  __shared__ __align__(16) bf16_t Ps[4][16 * 64];  //  8192 B  (total 40960)

  const int bid = blockIdx.x;
  const int g = bid & 31;             // (b,h) group; XCD = g & 7
  const int b = g >> 4, h = g & 15;
  const int v = bid >> 5, j = v & 7, sel = v >> 3;
  const int qt = (sel == 0) ? j : (sel == 1) ? 15 - j : (sel == 2) ? 16 + j : 31 - j;

  const int tid = threadIdx.x, lane = tid & 63, w = tid >> 6;
  const int qd = lane >> 4, ln = lane & 15;
  const bf16_t* Qb = C1 + (size_t)b * 2048 * 2048;

  // Q B-frags: lane (qd,ln): col=ln -> q, k=qd*8+j -> d (pre-scaled by SCL)
  bf16x8 qf0, qf1;
  {
    const bf16_t* qp = Qb + (size_t)(qt * 64 + w * 16 + ln) * 2048 + h * 64 + qd * 8;
    qf0 = *(const bf16x8*)qp;
    qf1 = *(const bf16x8*)(qp + 32);
  }
  const floatx4 z4 = {0.f, 0.f, 0.f, 0.f};
  floatx4 oacc[4];  // [t][r]: O[q_local=qd*4+r][hd=t*16+ln]
  #pragma unroll
  for (int t = 0; t < 4; ++t) oacc[t] = z4;
  floatx4 osum = z4;  // osum[r] = sum_s P[q=4qd+r][s], replicated over ln
  const bf16_t one = (bf16_t)1.0f;
  const bf16x8 vone = {one, one, one, one, one, one, one, one};

  const bf16_t* Kg = Qb + 1024 + h * 64;                       // + s*2048 + d
  const bf16_t* Vg = VT + (size_t)(h * 64) * 4096 + b * 2048;  // + hd*4096 + t

  const int r0 = tid >> 3;
  const int g0 = ((tid & 7) ^ (r0 & 7)) * 8;

  auto STAGE = [&](int BUF, int SOFF) {
    GLD16(Kg + (size_t)(SOFF + r0) * 2048 + g0,      &Ks[BUF][w * 512]);
    GLD16(Kg + (size_t)(SOFF + r0 + 32) * 2048 + g0, &Ks[BUF][w * 512 + 2048]);
    GLD16(Vg + (size_t)r0 * 4096 + SOFF + g0,        &Vs[BUF][w * 512]);
    GLD16(Vg + (size_t)(r0 + 32) * 4096 + SOFF + g0, &Vs[BUF][w * 512 + 2048]);
  };

  STAGE(0, 0);  // prologue: tile 0

  const int e2 = (ln & 7) << 1;       // Ps 8B-slot swizzle key
  const int swf = qd ^ (ln & 7);      // K/V frag slot swizzle (row&7 == ln&7)

  for (int st = 0; st <= qt; ++st) {
    const int bi = st & 1;
    __syncthreads();  // drains vmcnt: tile st staged; WAR-safe for buf bi^1
    if (st < qt) STAGE(bi ^ 1, (st + 1) * 64);

    // S^T = K Q^T : lane (qd,ln) gets P[q=ln][s=nt*16+qd*4+r]
    floatx4 sa[4];
    __builtin_amdgcn_s_setprio(1);
    #pragma unroll
    for (int nt = 0; nt < 4; ++nt) {
      const bf16_t* kp = &Ks[bi][(nt * 16 + ln) * 64];
      bf16x8 kf0 = *(const bf16x8*)(kp + swf * 8);
      bf16x8 kf1 = *(const bf16x8*)(kp + (swf ^ 4) * 8);
      floatx4 t0 = z4;
      t0 = __builtin_amdgcn_mfma_f32_16x16x32_bf16(kf0, qf0, t0, 0, 0, 0);
      t0 = __builtin_amdgcn_mfma_f32_16x16x32_bf16(kf1, qf1, t0, 0, 0, 0);
      sa[nt] = t0;
    }
    __builtin_amdgcn_s_setprio(0);

    // V-frag preload (independent of Ps round-trip): PV can start the
    // moment pa0/pa1 land.
    bf16x8 vf0[4], vf1[4];
    #pragma unroll
    for (int t = 0; t < 4; ++t) {
      const bf16_t* vp = &Vs[bi][(t * 16 + ln) * 64];
      vf0[t] = *(const bf16x8*)(vp + swf * 8);
      vf1[t] = *(const bf16x8*)(vp + (swf ^ 4) * 8);
    }

    // softmax -> Ps (swizzled, wave-private; in-wave DS order)
    #pragma unroll
    for (int nt = 0; nt < 4; ++nt) {
      float p[4];
      #pragma unroll
      for (int r = 0; r < 4; ++r) {
        float v2 = sa[nt][r];
        if (st == qt && (nt * 16 + qd * 4 + r) > (w * 16 + ln)) v2 = -1e30f;
        p[r] = __builtin_amdgcn_exp2f(v2);
      }
      bf16x4 pk = {(bf16_t)p[0], (bf16_t)p[1], (bf16_t)p[2], (bf16_t)p[3]};
      *(bf16x4*)(&Ps[w][ln * 64 + (((nt * 4 + qd) ^ e2) << 2)]) = pk;
    }
    bf16x8 pa0 = *(const bf16x8*)(&Ps[w][ln * 64 + ((((qd << 1)    ) ^ e2) << 2)]);
    bf16x8 pa1 = *(const bf16x8*)(&Ps[w][ln * 64 + ((((qd << 1) + 8) ^ e2) << 2)]);

    // PV: oacc += P * V;  osum += P * 1 (row sums on the MFMA pipe)
    __builtin_amdgcn_s_setprio(1);
    #pragma unroll
    for (int t = 0; t < 4; ++t) {
      oacc[t] = __builtin_amdgcn_mfma_f32_16x16x32_bf16(pa0, vf0[t], oacc[t], 0, 0, 0);
      oacc[t] = __builtin_amdgcn_mfma_f32_16x16x32_bf16(pa1, vf1[t], oacc[t], 0, 0, 0);
    }
    osum = __builtin_amdgcn_mfma_f32_16x16x32_bf16(pa0, vone, osum, 0, 0, 0);
    osum = __builtin_amdgcn_mfma_f32_16x16x32_bf16(pa1, vone, osum, 0, 0, 0);
    __builtin_amdgcn_s_setprio(0);
  }

  // epilogue: O[q][hd] /= l[q]; osum[r] already holds l(q=4qd+r) in-lane
  #pragma unroll
  for (int r = 0; r < 4; ++r) {
    const float lr = 1.0f / osum[r];
    #pragma unroll
    for (int t = 0; t < 4; ++t) {
      const int col = h * 64 + t * 16 + ln;
      const int row = b * 2048 + qt * 64 + w * 16 + qd * 4 + r;
      AO[(size_t)row * 1024 + col] = (bf16_t)(oacc[t][r] * lr);
    }
  }
}

// ---------------------------------------------------------------------------
extern "C" void kernel_launch(void* const* d_in, const int* in_sizes, int n_in,
                              void* d_out, int out_size, void* d_ws, size_t ws_size,
                              hipStream_t stream) {
  const float* x  = (const float*)d_in[0];
  const float* Wq = (const float*)d_in[1];
  const float* Wk = (const float*)d_in[2];
  const float* Wv = (const float*)d_in[3];
  const float* Wo = (const float*)d_in[4];
  const float* bo = (const float*)d_in[5];
  float* out = (float*)d_out;

  // Workspace (33.56 MB, proven safe):
  bf16_t* WT  = (bf16_t*)d_ws;               // [3072][1024] 6.29 MB (Q|K|V weight rows)
  bf16_t* WoT = WT + (size_t)3072 * 1024;    // [1024][1024] 2.10 MB
  bf16_t* C1  = WoT + (size_t)1024 * 1024;   // [4096][2048] 16.78 MB (Q|K cols)
  bf16_t* AO  = C1 + (size_t)4096 * 2048;    // [4096][1024] 8.39 MB
  // d_out doubles as scratch (16.78 MB; fully overwritten by final gemm):
  bf16_t* XB  = (bf16_t*)d_out;              // [4096][1024] bf16, lower half
  bf16_t* VT  = XB + (size_t)4096 * 1024;    // [1024][4096] bf16, upper half

  prep<<<dim3(3072), 256, 0, stream>>>(x, Wq, Wk, Wv, Wo, XB, WT, WoT);
  proj_gemm<<<dim3(768), 256, 0, stream>>>(XB, WT, C1, VT);
  flash_attn<<<dim3(1024), 256, 0, stream>>>(C1, VT, AO);
  out_gemm<<<dim3(32, 16), 256, 0, stream>>>(AO, WoT, out, bo);
}